// Round 3
// baseline (366.811 us; speedup 1.0000x reference)
//
#include <hip/hip_runtime.h>
#include <stdint.h>

#define ROWLEN 4096
#define KSEL   1024
#define NTHREADS 256
#define CANDCAP 256
typedef unsigned long long u64;

// Monotonic float->uint map: order(f) preserved as unsigned compare.
__device__ __forceinline__ uint32_t f2u_sortable(float f) {
    uint32_t u = __float_as_uint(f);
    return u ^ ((int32_t)u < 0 ? 0xFFFFFFFFu : 0x80000000u);
}

__device__ __forceinline__ void cmpex(u64 &a, u64 &b, bool maxFirst) {
    u64 mx = a > b ? a : b;
    u64 mn = a > b ? b : a;
    a = maxFirst ? mx : mn;
    b = maxFirst ? mn : mx;
}

// hist[NB] filled. Find digit d with S(d) < need <= S(d)+hist[d] where
// S(d) = #elements in bins > d. Writes sh_digit=d, sh_base=S(d). 2 barriers.
template<int NB>
__device__ void suffix_select(uint32_t* hist, int need, int tid,
                              int* sh_digit, int* sh_base, uint32_t* wavetot)
{
    constexpr int BPT = NB / NTHREADS;
    const int b0 = tid * BPT;
    uint32_t hh[BPT];
    uint32_t csum = 0;
#pragma unroll
    for (int b = 0; b < BPT; ++b) { hh[b] = hist[b0 + b]; csum += hh[b]; }
    const int lane = tid & 63;
    uint32_t incl = csum;                  // inclusive suffix over chunk sums in wave
#pragma unroll
    for (int off = 1; off < 64; off <<= 1) {
        uint32_t t = __shfl_down(incl, off);
        if (lane + off < 64) incl += t;
    }
    const int w = tid >> 6;
    if (lane == 0) wavetot[w] = incl;      // wave total
    __syncthreads();
    uint32_t later = 0;
    for (int ww = w + 1; ww < 4; ++ww) later += wavetot[ww];
    uint32_t run = (incl - csum) + later;  // elements in chunks after mine
#pragma unroll
    for (int b = BPT - 1; b >= 0; --b) {   // bins high -> low inside chunk
        uint32_t h = hh[b];
        if ((int)run < need && need <= (int)(run + h)) {
            *sh_digit = b0 + b;
            *sh_base  = (int)run;
        }
        run += h;
    }
    __syncthreads();
}

__global__ __launch_bounds__(NTHREADS) void adaptive_topk_kernel(
    const float* __restrict__ in, int* __restrict__ out_idx, int* __restrict__ out_k)
{
    __shared__ uint32_t sv[ROWLEN];        // 16 KB sortable values
    __shared__ u64 keysbuf[KSEL];          // 8 KB; aliased as hist during select
    __shared__ u64 cand[CANDCAP];          // 2 KB: keys with top-11 bits == d1
    __shared__ uint32_t wavetot[4];
    __shared__ double wsum[4], wsum2[4];
    __shared__ int sh_digit, sh_base, sh_cnt;

    uint32_t* hist = (uint32_t*)keysbuf;
    u64* keys = keysbuf;

    const int row  = blockIdx.x;
    const int tid  = threadIdx.x;
    const int lane = tid & 63;
    const float* __restrict__ rowp = in + (size_t)row * ROWLEN;
    const uint4 z0 = {0u, 0u, 0u, 0u};

    // ---- clear hist (2048 bins) ----
    ((uint4*)hist)[tid] = z0;
    ((uint4*)hist)[tid + 256] = z0;
    __syncthreads();

    // ---- load row: moments + sv + 11-bit histogram, fused ----
    double s = 0.0, s2 = 0.0;
    const float4* r4 = (const float4*)rowp;
    for (int i = tid; i < ROWLEN / 4; i += NTHREADS) {
        float4 v = r4[i];
        float ps  = (v.x + v.y) + (v.z + v.w);
        float ps2 = fmaf(v.x, v.x, fmaf(v.y, v.y, fmaf(v.z, v.z, v.w * v.w)));
        s  += (double)ps;
        s2 += (double)ps2;
        uint4 w;
        w.x = f2u_sortable(v.x);
        w.y = f2u_sortable(v.y);
        w.z = f2u_sortable(v.z);
        w.w = f2u_sortable(v.w);
        ((uint4*)sv)[i] = w;
        atomicAdd(&hist[w.x >> 21], 1u);
        atomicAdd(&hist[w.y >> 21], 1u);
        atomicAdd(&hist[w.z >> 21], 1u);
        atomicAdd(&hist[w.w >> 21], 1u);
    }
    // variance partial reduce (wave)
    for (int off = 32; off > 0; off >>= 1) {
        s  += __shfl_down(s, off);
        s2 += __shfl_down(s2, off);
    }
    if (lane == 0) { wsum[tid >> 6] = s; wsum2[tid >> 6] = s2; }
    __syncthreads();   // covers sv, hist, wsum
    if (tid == 0) {
        double S  = wsum[0] + wsum[1] + wsum[2] + wsum[3];
        double S2 = wsum2[0] + wsum2[1] + wsum2[2] + wsum2[3];
        double var = (S2 - S * S / (double)ROWLEN) / (double)(ROWLEN - 1);
        float sp = log1pf(expf((float)var));
        float ka = 512.0f * (1.0f + 0.1f * sp);
        ka = fminf(fmaxf(ka, 128.0f), 1024.0f);
        out_k[row] = (int)ka;
    }

    // ---- pass 1: top 11 bits ----
    suffix_select<2048>(hist, KSEL, tid, &sh_digit, &sh_base, wavetot);
    const int d1 = sh_digit;
    const int G1 = sh_base;
    const int rem1 = KSEL - G1;

    // ---- pass 2: next 11 bits among digit1==d1; build cand list ----
    if (tid == 0) sh_cnt = 0;
    ((uint4*)hist)[tid] = z0;
    ((uint4*)hist)[tid + 256] = z0;
    __syncthreads();
    for (int i4 = tid; i4 < ROWLEN / 4; i4 += NTHREADS) {
        uint4 w = ((const uint4*)sv)[i4];
        uint32_t vv[4] = {w.x, w.y, w.z, w.w};
#pragma unroll
        for (int e = 0; e < 4; ++e) {
            uint32_t v = vv[e];
            if ((int)(v >> 21) == d1) {
                int c = atomicAdd(&sh_cnt, 1);
                u64 K = ((u64)v << 12) | (u64)(ROWLEN - 1 - (4 * i4 + e));
                if (c < CANDCAP) cand[c] = K;
                atomicAdd(&hist[(v >> 10) & 0x7FF], 1u);   // always, even on overflow
            }
        }
    }
    __syncthreads();
    const int cnt2 = sh_cnt;
    const bool ovf = cnt2 > CANDCAP;
    suffix_select<2048>(hist, rem1, tid, &sh_digit, &sh_base, wavetot);
    const int d2 = sh_digit;
    const int G2 = sh_base;
    const int rem2 = rem1 - G2;
    const uint32_t pfx22 = (((uint32_t)d1) << 11) | (uint32_t)d2;

    // ---- pass 3: last 10 bits (cand-based; full scan only on overflow) ----
    ((uint4*)hist)[tid] = z0;              // 1024 bins
    __syncthreads();
    if (!ovf) {
        for (int e = tid; e < cnt2; e += NTHREADS) {
            uint32_t v = (uint32_t)(cand[e] >> 12);
            if ((v >> 10) == pfx22) atomicAdd(&hist[v & 0x3FF], 1u);
        }
    } else {
        for (int i4 = tid; i4 < ROWLEN / 4; i4 += NTHREADS) {
            uint4 w = ((const uint4*)sv)[i4];
            uint32_t vv[4] = {w.x, w.y, w.z, w.w};
#pragma unroll
            for (int e = 0; e < 4; ++e)
                if ((vv[e] >> 10) == pfx22) atomicAdd(&hist[vv[e] & 0x3FF], 1u);
        }
    }
    __syncthreads();
    suffix_select<1024>(hist, rem2, tid, &sh_digit, &sh_base, wavetot);
    const int d3 = sh_digit;
    const int G3 = sh_base;
    const int NG = G1 + G2 + G3;           // #elements with value > v*
    const int T  = rem2 - G3;              // #equal-to-v* to take (smallest indices)
    const uint32_t vstar = (pfx22 << 10) | (uint32_t)d3;
    if (tid == 0) sh_cnt = 0;
    __syncthreads();                       // hist done; keys writes may begin

    // ---- compact: v > v* via ballot-aggregated append ----
    const u64 lmask = (1ull << lane) - 1ull;
    for (int i4 = tid; i4 < ROWLEN / 4; i4 += NTHREADS) {
        uint4 w = ((const uint4*)sv)[i4];
        uint32_t vv[4] = {w.x, w.y, w.z, w.w};
#pragma unroll
        for (int e = 0; e < 4; ++e) {
            uint32_t v = vv[e];
            bool gt = v > vstar;
            u64 m = __ballot(gt);
            if (m) {
                int wbase;
                if (lane == 0) wbase = atomicAdd(&sh_cnt, __popcll(m));
                wbase = __shfl(wbase, 0);
                if (gt) keys[wbase + __popcll(m & lmask)] =
                            ((u64)v << 12) | (u64)(ROWLEN - 1 - (4 * i4 + e));
            }
        }
    }
    // ---- equals: take T smallest indices among elements == v* ----
    if (!ovf) {
        for (int e = tid; e < cnt2; e += NTHREADS) {
            u64 K = cand[e];
            if ((uint32_t)(K >> 12) == vstar) {
                int r = 0;
                for (int j = 0; j < cnt2; ++j) {
                    u64 Kj = cand[j];
                    r += (Kj > K) && ((uint32_t)(Kj >> 12) == vstar);
                }
                if (r < T) keys[NG + r] = K;   // larger K = smaller idx
            }
        }
    } else if (tid == 0) {                 // degenerate fallback
        int taken = 0;
        for (int i = 0; i < ROWLEN && taken < T; ++i)
            if (sv[i] == vstar) { keys[NG + taken] = ((u64)vstar << 12) | (u64)(ROWLEN - 1 - i); ++taken; }
    }
    __syncthreads();

    // ---- bitonic sort 1024 keys descending: 4 keys/thread in registers,
    //      j=1,2 in-reg, j=4..128 shfl_xor, j=256,512 via LDS ----
    u64 r[4];
#pragma unroll
    for (int e = 0; e < 4; ++e) r[e] = keys[(tid << 2) | e];

#pragma unroll
    for (int k = 2; k <= KSEL; k <<= 1) {
#pragma unroll
        for (int j = k >> 1; j > 0; j >>= 1) {
            if (j >= 256) {
#pragma unroll
                for (int e = 0; e < 4; ++e) keys[(tid << 2) | e] = r[e];
                __syncthreads();
                u64 o[4];
#pragma unroll
                for (int e = 0; e < 4; ++e) o[e] = keys[((tid << 2) | e) ^ j];
                __syncthreads();
#pragma unroll
                for (int e = 0; e < 4; ++e) {
                    int i = (tid << 2) | e;
                    bool takeMax = (((i & j) == 0) == ((i & k) == 0));
                    r[e] = ((r[e] > o[e]) == takeMax) ? r[e] : o[e];   // keys distinct
                }
            } else if (j >= 4) {
                int msk = j >> 2;
#pragma unroll
                for (int e = 0; e < 4; ++e) {
                    u64 o = __shfl_xor(r[e], msk);
                    int i = (tid << 2) | e;
                    bool takeMax = (((i & j) == 0) == ((i & k) == 0));
                    r[e] = ((r[e] > o) == takeMax) ? r[e] : o;
                }
            } else if (j == 2) {
                int base = tid << 2;
                cmpex(r[0], r[2], ((base | 0) & k) == 0);
                cmpex(r[1], r[3], ((base | 1) & k) == 0);
            } else {
                int base = tid << 2;
                cmpex(r[0], r[1], ((base | 0) & k) == 0);
                cmpex(r[2], r[3], ((base | 2) & k) == 0);
            }
        }
    }

    // ---- write indices (coalesced int4 straight from registers) ----
    int4 ov;
    ov.x = (ROWLEN - 1) - (int)(r[0] & 0xFFFu);
    ov.y = (ROWLEN - 1) - (int)(r[1] & 0xFFFu);
    ov.z = (ROWLEN - 1) - (int)(r[2] & 0xFFFu);
    ov.w = (ROWLEN - 1) - (int)(r[3] & 0xFFFu);
    ((int4*)(out_idx + (size_t)row * KSEL))[tid] = ov;
}

extern "C" void kernel_launch(void* const* d_in, const int* in_sizes, int n_in,
                              void* d_out, int out_size, void* d_ws, size_t ws_size,
                              hipStream_t stream) {
    const float* in = (const float*)d_in[0];
    const int B = in_sizes[0] / (ROWLEN * ROWLEN);   // 4
    const int nrows = B * ROWLEN;                    // 16384
    int* out = (int*)d_out;
    int* out_idx = out;                              // B*L*KSEL
    int* out_k   = out + (size_t)nrows * KSEL;       // B*L
    adaptive_topk_kernel<<<dim3(nrows), dim3(NTHREADS), 0, stream>>>(in, out_idx, out_k);
}

// Round 4
// 338.082 us; speedup vs baseline: 1.0850x; 1.0850x over previous
//
#include <hip/hip_runtime.h>
#include <stdint.h>

#define ROWLEN 4096
#define KSEL   1024
#define NTHREADS 256
#define CANDCAP 256
typedef unsigned long long u64;

// Monotonic float->uint map: order(f) preserved as unsigned compare.
__device__ __forceinline__ uint32_t f2u_sortable(float f) {
    uint32_t u = __float_as_uint(f);
    return u ^ ((int32_t)u < 0 ? 0xFFFFFFFFu : 0x80000000u);
}

// Bank-conflict swizzle for keys[1024] (u64): mixes bits 4-7 into bits 0-3.
// Bijective on [0,1024); swz(i^j) == swz(i)^j for j >= 256.
__device__ __forceinline__ int swz(int i) { return i ^ ((i >> 4) & 15); }

__device__ __forceinline__ void cmpex(u64 &a, u64 &b, bool maxFirst) {
    u64 mx = a > b ? a : b;
    u64 mn = a > b ? b : a;
    a = maxFirst ? mx : mn;
    b = maxFirst ? mn : mx;
}

// hist[NB] filled. Find digit d with S(d) < need <= S(d)+hist[d] where
// S(d) = #elements in bins > d. Writes sh_digit=d, sh_base=S(d). 2 barriers.
template<int NB>
__device__ void suffix_select(uint32_t* hist, int need, int tid,
                              int* sh_digit, int* sh_base, uint32_t* wavetot)
{
    constexpr int BPT = NB / NTHREADS;
    const int b0 = tid * BPT;
    uint32_t hh[BPT];
    uint32_t csum = 0;
#pragma unroll
    for (int b = 0; b < BPT; ++b) { hh[b] = hist[b0 + b]; csum += hh[b]; }
    const int lane = tid & 63;
    uint32_t incl = csum;                  // inclusive suffix over chunk sums in wave
#pragma unroll
    for (int off = 1; off < 64; off <<= 1) {
        uint32_t t = __shfl_down(incl, off);
        if (lane + off < 64) incl += t;
    }
    const int w = tid >> 6;
    if (lane == 0) wavetot[w] = incl;      // wave total
    __syncthreads();
    uint32_t later = 0;
    for (int ww = w + 1; ww < 4; ++ww) later += wavetot[ww];
    uint32_t run = (incl - csum) + later;  // elements in chunks after mine
#pragma unroll
    for (int b = BPT - 1; b >= 0; --b) {   // bins high -> low inside chunk
        uint32_t h = hh[b];
        if ((int)run < need && need <= (int)(run + h)) {
            *sh_digit = b0 + b;
            *sh_base  = (int)run;
        }
        run += h;
    }
    __syncthreads();
}

__global__ __launch_bounds__(NTHREADS, 8) void adaptive_topk_kernel(
    const float* __restrict__ in, int* __restrict__ out_idx, int* __restrict__ out_k)
{
    __shared__ u64 keysbuf[KSEL];          // 8 KB; aliased as hist during select
    __shared__ u64 cand[CANDCAP];          // 2 KB: keys with top-11 bits == d1
    __shared__ uint32_t wavetot[4];
    __shared__ float wsum[4], wsum2[4];
    __shared__ int sh_digit, sh_base, sh_cnt;

    uint32_t* hist = (uint32_t*)keysbuf;
    u64* keys = keysbuf;

    const int row  = blockIdx.x;
    const int tid  = threadIdx.x;
    const int lane = tid & 63;
    const float* __restrict__ rowp = in + (size_t)row * ROWLEN;
    const uint4 z0 = {0u, 0u, 0u, 0u};

    // ---- clear hist (2048 bins) ----
    ((uint4*)hist)[tid] = z0;
    ((uint4*)hist)[tid + 256] = z0;
    __syncthreads();

    // ---- load row into REGISTERS: moments + 11-bit histogram, fused ----
    // w[it] component e holds element idx = 4*(tid + 256*it) + e
    uint4 w[4];
    float s = 0.0f, s2 = 0.0f;
    const float4* r4 = (const float4*)rowp;
#pragma unroll
    for (int it = 0; it < 4; ++it) {
        float4 v = r4[tid + 256 * it];
        s  += (v.x + v.y) + (v.z + v.w);
        s2  = fmaf(v.x, v.x, fmaf(v.y, v.y, fmaf(v.z, v.z, fmaf(v.w, v.w, s2))));
        w[it].x = f2u_sortable(v.x);
        w[it].y = f2u_sortable(v.y);
        w[it].z = f2u_sortable(v.z);
        w[it].w = f2u_sortable(v.w);
        atomicAdd(&hist[w[it].x >> 21], 1u);
        atomicAdd(&hist[w[it].y >> 21], 1u);
        atomicAdd(&hist[w[it].z >> 21], 1u);
        atomicAdd(&hist[w[it].w >> 21], 1u);
    }
    // variance partial reduce (wave, f32)
    for (int off = 32; off > 0; off >>= 1) {
        s  += __shfl_down(s, off);
        s2 += __shfl_down(s2, off);
    }
    if (lane == 0) { wsum[tid >> 6] = s; wsum2[tid >> 6] = s2; }
    __syncthreads();   // covers hist, wsum
    if (tid == 0) {
        double S  = (double)wsum[0] + wsum[1] + wsum[2] + wsum[3];
        double S2 = (double)wsum2[0] + wsum2[1] + wsum2[2] + wsum2[3];
        double var = (S2 - S * S / (double)ROWLEN) / (double)(ROWLEN - 1);
        float sp = log1pf(expf((float)var));
        float ka = 512.0f * (1.0f + 0.1f * sp);
        ka = fminf(fmaxf(ka, 128.0f), 1024.0f);
        out_k[row] = (int)ka;
    }

    // ---- pass 1: top 11 bits ----
    suffix_select<2048>(hist, KSEL, tid, &sh_digit, &sh_base, wavetot);
    const int d1 = sh_digit;
    const int G1 = sh_base;
    const int rem1 = KSEL - G1;

    // ---- pass 2: next 11 bits among digit1==d1; build cand list (from regs) ----
    if (tid == 0) sh_cnt = 0;
    ((uint4*)hist)[tid] = z0;
    ((uint4*)hist)[tid + 256] = z0;
    __syncthreads();
#pragma unroll
    for (int it = 0; it < 4; ++it) {
        uint32_t vv[4] = {w[it].x, w[it].y, w[it].z, w[it].w};
#pragma unroll
        for (int e = 0; e < 4; ++e) {
            uint32_t v = vv[e];
            if ((int)(v >> 21) == d1) {
                int c = atomicAdd(&sh_cnt, 1);
                int idx = 4 * (tid + 256 * it) + e;
                u64 K = ((u64)v << 12) | (u64)(ROWLEN - 1 - idx);
                if (c < CANDCAP) cand[c] = K;
                atomicAdd(&hist[(v >> 10) & 0x7FF], 1u);   // always, even on overflow
            }
        }
    }
    __syncthreads();
    const int cnt2 = sh_cnt;
    const bool ovf = cnt2 > CANDCAP;
    suffix_select<2048>(hist, rem1, tid, &sh_digit, &sh_base, wavetot);
    const int d2 = sh_digit;
    const int G2 = sh_base;
    const int rem2 = rem1 - G2;
    const uint32_t pfx22 = (((uint32_t)d1) << 11) | (uint32_t)d2;

    // ---- pass 3: last 10 bits (cand-based; global rescan only on overflow) ----
    ((uint4*)hist)[tid] = z0;              // 1024 bins
    __syncthreads();
    if (!ovf) {
        for (int e = tid; e < cnt2; e += NTHREADS) {
            uint32_t v = (uint32_t)(cand[e] >> 12);
            if ((v >> 10) == pfx22) atomicAdd(&hist[v & 0x3FF], 1u);
        }
    } else {
#pragma unroll
        for (int it = 0; it < 4; ++it) {
            uint32_t vv[4] = {w[it].x, w[it].y, w[it].z, w[it].w};
#pragma unroll
            for (int e = 0; e < 4; ++e)
                if ((vv[e] >> 10) == pfx22) atomicAdd(&hist[vv[e] & 0x3FF], 1u);
        }
    }
    __syncthreads();
    if (tid == 0) sh_cnt = 0;              // made visible by suffix_select barriers
    suffix_select<1024>(hist, rem2, tid, &sh_digit, &sh_base, wavetot);
    const int d3 = sh_digit;
    const int G3 = sh_base;
    const int NG = G1 + G2 + G3;           // #elements with value > v*
    const int T  = rem2 - G3;              // #equal-to-v* to take (smallest indices)
    const uint32_t vstar = (pfx22 << 10) | (uint32_t)d3;

    // ---- compact: v > v* via ballot-aggregated append (from regs, swizzled) ----
    const u64 lmask = (1ull << lane) - 1ull;
#pragma unroll
    for (int it = 0; it < 4; ++it) {
        uint32_t vv[4] = {w[it].x, w[it].y, w[it].z, w[it].w};
#pragma unroll
        for (int e = 0; e < 4; ++e) {
            uint32_t v = vv[e];
            bool gt = v > vstar;
            u64 m = __ballot(gt);
            if (m) {
                int wbase;
                if (lane == 0) wbase = atomicAdd(&sh_cnt, __popcll(m));
                wbase = __shfl(wbase, 0);
                if (gt) {
                    int idx = 4 * (tid + 256 * it) + e;
                    keys[swz(wbase + __popcll(m & lmask))] =
                        ((u64)v << 12) | (u64)(ROWLEN - 1 - idx);
                }
            }
        }
    }
    // ---- equals: take T smallest indices among elements == v* ----
    if (!ovf) {
        for (int e = tid; e < cnt2; e += NTHREADS) {
            u64 K = cand[e];
            if ((uint32_t)(K >> 12) == vstar) {
                int r = 0;
                for (int j = 0; j < cnt2; ++j) {
                    u64 Kj = cand[j];
                    r += (Kj > K) && ((uint32_t)(Kj >> 12) == vstar);
                }
                if (r < T) keys[swz(NG + r)] = K;   // larger K = smaller idx
            }
        }
    } else if (tid == 0) {                 // degenerate fallback: reread global
        int taken = 0;
        for (int i = 0; i < ROWLEN && taken < T; ++i) {
            uint32_t v = f2u_sortable(rowp[i]);
            if (v == vstar) {
                keys[swz(NG + taken)] = ((u64)vstar << 12) | (u64)(ROWLEN - 1 - i);
                ++taken;
            }
        }
    }
    __syncthreads();

    // ---- bitonic sort 1024 keys descending: 4 keys/thread in registers,
    //      j=1,2 in-reg, j=4..128 shfl_xor, j=256,512 via swizzled LDS ----
    u64 r[4];
#pragma unroll
    for (int e = 0; e < 4; ++e) r[e] = keys[swz((tid << 2) | e)];

#pragma unroll
    for (int k = 2; k <= KSEL; k <<= 1) {
#pragma unroll
        for (int j = k >> 1; j > 0; j >>= 1) {
            if (j >= 256) {
#pragma unroll
                for (int e = 0; e < 4; ++e) keys[swz((tid << 2) | e)] = r[e];
                __syncthreads();
                u64 o[4];
#pragma unroll
                for (int e = 0; e < 4; ++e) o[e] = keys[swz(((tid << 2) | e) ^ j)];
                __syncthreads();
#pragma unroll
                for (int e = 0; e < 4; ++e) {
                    int i = (tid << 2) | e;
                    bool takeMax = (((i & j) == 0) == ((i & k) == 0));
                    r[e] = ((r[e] > o[e]) == takeMax) ? r[e] : o[e];   // keys distinct
                }
            } else if (j >= 4) {
                int msk = j >> 2;
#pragma unroll
                for (int e = 0; e < 4; ++e) {
                    u64 o = __shfl_xor(r[e], msk);
                    int i = (tid << 2) | e;
                    bool takeMax = (((i & j) == 0) == ((i & k) == 0));
                    r[e] = ((r[e] > o) == takeMax) ? r[e] : o;
                }
            } else if (j == 2) {
                int base = tid << 2;
                cmpex(r[0], r[2], ((base | 0) & k) == 0);
                cmpex(r[1], r[3], ((base | 1) & k) == 0);
            } else {
                int base = tid << 2;
                cmpex(r[0], r[1], ((base | 0) & k) == 0);
                cmpex(r[2], r[3], ((base | 2) & k) == 0);
            }
        }
    }

    // ---- write indices (coalesced int4 straight from registers) ----
    int4 ov;
    ov.x = (ROWLEN - 1) - (int)(r[0] & 0xFFFu);
    ov.y = (ROWLEN - 1) - (int)(r[1] & 0xFFFu);
    ov.z = (ROWLEN - 1) - (int)(r[2] & 0xFFFu);
    ov.w = (ROWLEN - 1) - (int)(r[3] & 0xFFFu);
    ((int4*)(out_idx + (size_t)row * KSEL))[tid] = ov;
}

extern "C" void kernel_launch(void* const* d_in, const int* in_sizes, int n_in,
                              void* d_out, int out_size, void* d_ws, size_t ws_size,
                              hipStream_t stream) {
    const float* in = (const float*)d_in[0];
    const int B = in_sizes[0] / (ROWLEN * ROWLEN);   // 4
    const int nrows = B * ROWLEN;                    // 16384
    int* out = (int*)d_out;
    int* out_idx = out;                              // B*L*KSEL
    int* out_k   = out + (size_t)nrows * KSEL;       // B*L
    adaptive_topk_kernel<<<dim3(nrows), dim3(NTHREADS), 0, stream>>>(in, out_idx, out_k);
}